// Round 10
// baseline (250.629 us; speedup 1.0000x reference)
//
#include <hip/hip_runtime.h>

#define N_NODES 100000
#define N_FEATS 256
#define OUT_DIM 64
#define NNZ_X   1280000
#define N_EDGES 1600000
#define NB2     782     // ceil(N_NODES/128); bucket = row >> 7
#define CHUNK   4096    // entries per phase-1 block (512 thr, 8/thread)
#define CAPX2   2176    // X slab capacity (kept-mean 1475, sigma 38: +18 sigma)
#define CAPA2   2560    // A slab capacity (mean 2048, sigma 45: +11 sigma)

// ---------------- JAX threefry2x32 (partitionable mode, verified R2) ----------------
__device__ __forceinline__ unsigned rotl32(unsigned x, unsigned d) {
    return (x << d) | (x >> (32u - d));
}

__device__ __forceinline__ float jax_uniform_42(unsigned e) {
    unsigned x0 = 0u, x1 = e;
    const unsigned ks0 = 0u, ks1 = 42u, ks2 = 0u ^ 42u ^ 0x1BD11BDAu;
    x0 += ks0; x1 += ks1;
#define TF_R(r) { x0 += x1; x1 = rotl32(x1, r); x1 ^= x0; }
    TF_R(13) TF_R(15) TF_R(26) TF_R(6)
    x0 += ks1; x1 += ks2 + 1u;
    TF_R(17) TF_R(29) TF_R(16) TF_R(24)
    x0 += ks2; x1 += ks0 + 2u;
    TF_R(13) TF_R(15) TF_R(26) TF_R(6)
    x0 += ks0; x1 += ks1 + 3u;
    TF_R(17) TF_R(29) TF_R(16) TF_R(24)
    x0 += ks1; x1 += ks2 + 4u;
    TF_R(13) TF_R(15) TF_R(26) TF_R(6)
    x0 += ks2; x1 += ks0 + 5u;
#undef TF_R
    unsigned bits = x0 ^ x1;
    return __uint_as_float((bits >> 9) | 0x3f800000u) - 1.0f;
}

__device__ __forceinline__ bool keep_42(unsigned e) {
    float u = jax_uniform_42(e);
    return floorf(0.9f + u) != 0.0f;
}

// ---------------- phase 1: LDS-binned bucket grouping into fixed slabs --------
// Entry: float2(val, int(col<<7 | row&127)). Slab b = dst[b*CAP .. b*CAP+cnt_b).
// rows read ONCE (register cache + keep flag); dropped X entries skipped.
__global__ __launch_bounds__(512) void phase1(
        const float* __restrict__ fvals, const int* __restrict__ frows,
        const int* __restrict__ fcols,
        const float* __restrict__ avals, const int* __restrict__ arows,
        const int* __restrict__ acols,
        int* __restrict__ bcur_x, int* __restrict__ bcur_a,
        float2* __restrict__ gx, float2* __restrict__ ga) {
    const int isA = blockIdx.y;
    const float* vals = isA ? avals : fvals;
    const int* rows   = isA ? arows : frows;
    const int* cols   = isA ? acols : fcols;
    int* bcur         = isA ? bcur_a : bcur_x;
    float2* dst       = isA ? ga : gx;
    const unsigned cap = isA ? CAPA2 : CAPX2;
    const unsigned n  = isA ? N_EDGES : NNZ_X;

    unsigned t = threadIdx.x;
    unsigned base = blockIdx.x * CHUNK;
    if (base >= n) return;   // uniform per block (X side has fewer chunks)

    __shared__ int cnt[1024];
    __shared__ int start[1024];
    __shared__ int cur[1024];
    __shared__ int gbase[1024];
    __shared__ int s[512];
    __shared__ unsigned pArr[CHUNK];   // (b<<19)|(rowlow<<12)|ilocal

    int rcache[8];                     // row if kept, else -1

    cnt[t] = 0; cnt[t + 512] = 0;
    __syncthreads();
    // pass 1: read rows once, hist kept entries per bucket
    #pragma unroll
    for (int k = 0; k < 8; k++) {
        unsigned i = base + k * 512u + t;
        int r = -1;
        if (i < n) {
            int rr = rows[i];
            if (isA || keep_42(i)) r = rr;
        }
        rcache[k] = r;
        if (r >= 0) atomicAdd(&cnt[(unsigned)r >> 7], 1);
    }
    __syncthreads();
    // exclusive scan of 1024 bins (2 / thread)
    s[t] = cnt[2*t] + cnt[2*t+1];
    __syncthreads();
    for (int off = 1; off < 512; off <<= 1) {
        int v = (t >= (unsigned)off) ? s[t - off] : 0;
        __syncthreads();
        s[t] += v;
        __syncthreads();
    }
    int excl = t ? s[t-1] : 0;
    int n_valid = s[511];
    start[2*t]   = excl;
    start[2*t+1] = excl + cnt[2*t];
    cur[2*t]     = excl;
    cur[2*t+1]   = excl + cnt[2*t];
    for (unsigned b = t; b < NB2; b += 512u) {
        int cb = cnt[b];
        if (cb > 0) gbase[b] = atomicAdd(&bcur[b], cb);
    }
    __syncthreads();
    // pass 2: bucket-grouped permutation from the register cache (no re-read)
    #pragma unroll
    for (int k = 0; k < 8; k++) {
        int r = rcache[k];
        if (r >= 0) {
            unsigned b = (unsigned)r >> 7;
            int p = atomicAdd(&cur[b], 1);
            pArr[p] = (b << 19) | (((unsigned)r & 127u) << 12) | (k * 512u + t);
        }
    }
    __syncthreads();
    // pass 3: coalesced slab writes; gather cols/vals from the 16KB window
    #pragma unroll
    for (int k = 0; k < 8; k++) {
        int sidx = k * 512 + (int)t;
        if (sidx < n_valid) {
            unsigned m = pArr[sidx];
            unsigned b = m >> 19;
            unsigned rowlow = (m >> 12) & 127u;
            unsigned i = base + (m & 4095u);
            float v = vals[i];
            if (!isA) v *= (float)(1.0 / 0.9);
            unsigned packed = ((unsigned)cols[i] << 7) | rowlow;
            float2 e; e.x = v; e.y = __int_as_float((int)packed);
            dst[(size_t)b * cap + gbase[b] + (sidx - start[b])] = e;
        }
    }
}

// ---------------- sortXA: in-place per-bucket row sort, register-staged -------
// blocks [0,NB2): X slabs; [NB2,2*NB2): A slabs. All global reads complete
// before the scan barrier; writes after -> in-place safe. Rewrites entries as
// (val, col); emits local row starts (ushort).
__global__ __launch_bounds__(256) void sortXA(
        const int* __restrict__ bcur_x, float2* __restrict__ gx,
        unsigned short* __restrict__ rs_x,
        const int* __restrict__ bcur_a, float2* __restrict__ ga,
        unsigned short* __restrict__ rs_a) {
    __shared__ int hist[256];
    __shared__ int cursor[256];
    unsigned t = threadIdx.x;
    const int isA = (blockIdx.x >= NB2);
    unsigned b = isA ? (blockIdx.x - NB2) : blockIdx.x;
    int cnt = isA ? bcur_a[b] : bcur_x[b];
    float2* g = isA ? (ga + (size_t)b * CAPA2) : (gx + (size_t)b * CAPX2);
    unsigned short* rs = isA ? rs_a : rs_x;

    hist[t] = 0;
    __syncthreads();
    // read ALL entries into registers + histogram rowlow (bins 128..255 stay 0)
    float2 ec[10];
    #pragma unroll
    for (int k = 0; k < 10; k++) {
        int i = k * 256 + (int)t;
        if (i < cnt) {
            float2 e = g[i];
            ec[k] = e;
            atomicAdd(&hist[((unsigned)__float_as_int(e.y)) & 127u], 1);
        }
    }
    __syncthreads();
    // exclusive scan over 256 bins
    for (int off = 1; off < 256; off <<= 1) {
        int v = (t >= (unsigned)off) ? hist[t - off] : 0;
        __syncthreads();
        hist[t] += v;
        __syncthreads();
    }
    int excl = t ? hist[t - 1] : 0;
    cursor[t] = excl;
    if (t < 128u) rs[(b << 7) + t] = (unsigned short)excl;
    __syncthreads();
    // claim destination positions
    int pos[10];
    #pragma unroll
    for (int k = 0; k < 10; k++) {
        int i = k * 256 + (int)t;
        pos[k] = (i < cnt)
            ? atomicAdd(&cursor[((unsigned)__float_as_int(ec[k].y)) & 127u], 1)
            : -1;
    }
    // write back sorted, (val, col) format (reads all finished pre-scan)
    #pragma unroll
    for (int k = 0; k < 10; k++) {
        if (pos[k] >= 0) {
            unsigned packed = (unsigned)__float_as_int(ec[k].y);
            float2 o; o.x = ec[k].x; o.y = __int_as_float((int)(packed >> 7));
            g[pos[k]] = o;
        }
    }
}

// ---------------- SpMM1: wave per row, unroll 8, W gather (L1/L2-hot) ---------
__global__ void spmm1(const int* __restrict__ bcur_x,
                      const unsigned short* __restrict__ rs_x,
                      const float2* __restrict__ gx,
                      const float* __restrict__ W,
                      unsigned short* __restrict__ xw) {
    unsigned row  = blockIdx.x * 4u + (threadIdx.x >> 6);
    unsigned lane = threadIdx.x & 63u;
    if (row >= N_NODES) return;
    unsigned b = row >> 7, rl = row & 127u;
    int cnt = bcur_x[b];
    const float2* ent = gx + (size_t)b * CAPX2;
    int s0 = rs_x[row];
    int s1 = (rl == 127u) ? cnt : (int)rs_x[row + 1];
    float a[8];
    #pragma unroll
    for (int j = 0; j < 8; j++) a[j] = 0.0f;
    int p = s0;
    for (; p + 8 <= s1; p += 8) {
        float2 e[8];
        #pragma unroll
        for (int j = 0; j < 8; j++) e[j] = ent[p + j];
        float w[8];
        #pragma unroll
        for (int j = 0; j < 8; j++)
            w[j] = W[((unsigned)__float_as_int(e[j].y)) * OUT_DIM + lane];
        #pragma unroll
        for (int j = 0; j < 8; j++) a[j] = fmaf(e[j].x, w[j], a[j]);
    }
    for (; p < s1; p++) {
        float2 e = ent[p];
        a[0] = fmaf(e.x, W[((unsigned)__float_as_int(e.y)) * OUT_DIM + lane], a[0]);
    }
    float acc = ((a[0] + a[1]) + (a[2] + a[3])) + ((a[4] + a[5]) + (a[6] + a[7]));
    unsigned bits = __float_as_uint(acc);
    unsigned rounded = (bits + 0x7fffu + ((bits >> 16) & 1u)) >> 16;
    xw[(size_t)row * OUT_DIM + lane] = (unsigned short)rounded;
}

// ---------------- SpMM2 + ReLU: wave per row, unroll 16, bf16 xw gather --------
__global__ void spmm2(const int* __restrict__ bcur_a,
                      const unsigned short* __restrict__ rs_a,
                      const float2* __restrict__ ga,
                      const unsigned short* __restrict__ xw,
                      float* __restrict__ out) {
    unsigned row  = blockIdx.x * 4u + (threadIdx.x >> 6);
    unsigned lane = threadIdx.x & 63u;
    if (row >= N_NODES) return;
    unsigned b = row >> 7, rl = row & 127u;
    int cnt = bcur_a[b];
    const float2* ent = ga + (size_t)b * CAPA2;
    int s0 = rs_a[row];
    int s1 = (rl == 127u) ? cnt : (int)rs_a[row + 1];
    float a[8];
    #pragma unroll
    for (int j = 0; j < 8; j++) a[j] = 0.0f;
    int p = s0;
    for (; p + 16 <= s1; p += 16) {
        float2 e[16];
        #pragma unroll
        for (int j = 0; j < 16; j++) e[j] = ent[p + j];
        float x[16];
        #pragma unroll
        for (int j = 0; j < 16; j++)
            x[j] = __uint_as_float((unsigned)xw[((unsigned)__float_as_int(e[j].y)) * OUT_DIM + lane] << 16);
        #pragma unroll
        for (int j = 0; j < 16; j++)
            a[j & 7] = fmaf(e[j].x, x[j], a[j & 7]);
    }
    for (; p + 4 <= s1; p += 4) {
        float2 e[4];
        #pragma unroll
        for (int j = 0; j < 4; j++) e[j] = ent[p + j];
        #pragma unroll
        for (int j = 0; j < 4; j++) {
            float x = __uint_as_float((unsigned)xw[((unsigned)__float_as_int(e[j].y)) * OUT_DIM + lane] << 16);
            a[j] = fmaf(e[j].x, x, a[j]);
        }
    }
    for (; p < s1; p++) {
        float2 e = ent[p];
        float x = __uint_as_float((unsigned)xw[((unsigned)__float_as_int(e.y)) * OUT_DIM + lane] << 16);
        a[0] = fmaf(e.x, x, a[0]);
    }
    float acc = ((a[0] + a[1]) + (a[2] + a[3])) + ((a[4] + a[5]) + (a[6] + a[7]));
    out[(size_t)row * OUT_DIM + lane] = fmaxf(acc, 0.0f);
}

extern "C" void kernel_launch(void* const* d_in, const int* in_sizes, int n_in,
                              void* d_out, int out_size, void* d_ws, size_t ws_size,
                              hipStream_t stream) {
    const float* feat_values = (const float*)d_in[0];
    const float* W           = (const float*)d_in[1];
    const float* adj_values  = (const float*)d_in[2];
    const int*   feat_rows   = (const int*)d_in[3];
    const int*   feat_cols   = (const int*)d_in[4];
    const int*   adj_rows    = (const int*)d_in[5];
    const int*   adj_cols    = (const int*)d_in[6];
    float* out = (float*)d_out;

    // ---- workspace layout (bytes), total ~42.8 MB ----
    // bcur_x @ 0        (1024 ints)
    // bcur_a @ 4096     (1024 ints)
    // rs_x   @ 8192     (100096 ushort = 200,192)
    // rs_a   @ 208384   (200,192)
    // gx     @ 409600   (782*CAPX2*8 = 13,613,056)
    // ga     @ 14,022,656 (782*CAPA2*8 = 16,015,360)
    // xw     @ 30,038,016 (100000*64*2 = 12,800,000)
    char* ws = (char*)d_ws;
    int* bcur_x = (int*)(ws + 0);
    int* bcur_a = (int*)(ws + 4096);
    unsigned short* rs_x = (unsigned short*)(ws + 8192);
    unsigned short* rs_a = (unsigned short*)(ws + 208384);
    float2* gx  = (float2*)(ws + 409600);
    float2* ga  = (float2*)(ws + 14022656);
    unsigned short* xw = (unsigned short*)(ws + 30038016);

    hipMemsetAsync(ws, 0, 8192, stream);    // bucket cursors

    // phase1: grid sized for the larger (A) side; X blocks past 313 early-exit
    dim3 gp1((N_EDGES + CHUNK - 1) / CHUNK, 2);
    phase1<<<gp1, 512, 0, stream>>>(feat_values, feat_rows, feat_cols,
                                    adj_values, adj_rows, adj_cols,
                                    bcur_x, bcur_a, gx, ga);
    sortXA<<<2 * NB2, 256, 0, stream>>>(bcur_x, gx, rs_x, bcur_a, ga, rs_a);
    spmm1<<<(N_NODES + 3) / 4, 256, 0, stream>>>(bcur_x, rs_x, gx, W, xw);
    spmm2<<<(N_NODES + 3) / 4, 256, 0, stream>>>(bcur_a, rs_a, ga, xw, out);
}